// Round 1
// baseline (195.812 us; speedup 1.0000x reference)
//
#include <hip/hip_runtime.h>

typedef unsigned short u16;
typedef short bf16x8 __attribute__((ext_vector_type(8)));
typedef float floatx4 __attribute__((ext_vector_type(4)));

#define OUT_CTX 16777216           // 2*128*65536 attention elems
#define OUT_CLS (OUT_CTX + 512)

__device__ __forceinline__ u16 f2b(float f) {           // fp32 -> bf16 RNE
  unsigned int u = __float_as_uint(f);
  u += 0x7fffu + ((u >> 16) & 1u);
  return (u16)(u >> 16);
}
__device__ __forceinline__ float b2f(u16 b) { return __uint_as_float(((unsigned int)b) << 16); }

// ---- prepack: W (128x128) -> A-fragment-linear bf16 [rb][ks][lane][8]
// A layout for mfma_f32_16x16x32_bf16: A[m = lane&15][k = (lane>>4)*8 + j]
__device__ __forceinline__ float pack_val(const float* W, int eo) {
  int mt = eo >> 11;
  int rem = eo & 2047;
  int ks = rem >> 9;
  int lane = (rem >> 3) & 63;
  int j = rem & 7;
  int row = mt * 16 + (lane & 15);
  int col = ks * 32 + (lane >> 4) * 8 + j;
  return W[row * 128 + col];
}

__global__ __launch_bounds__(256) void kP(
    const float* __restrict__ Wk, const float* __restrict__ Wq,
    const float* __restrict__ Wv, const float* __restrict__ CLS,
    float* __restrict__ S2, float* __restrict__ Cnum2,
    u16* __restrict__ wkv, u16* __restrict__ wqf) {
  const int t = threadIdx.x;
  if (blockIdx.x < 24) {
    #pragma unroll
    for (int i = 0; i < 8; ++i) {
      int e = blockIdx.x * 2048 + i * 256 + t;            // 0..49151
      if (e < 32768) {                                    // rb 0..7 = Wk, 8..15 = Wv
        wkv[e] = f2b(pack_val(e < 16384 ? Wk : Wv, e & 16383));
      } else {
        wqf[e - 32768] = f2b(pack_val(Wq, e - 32768));
      }
    }
  } else {
    // init S / Cnum slot0 with the 4 CLS columns' contributions, slots 1..3 = 0
    int nn = t >> 7, r = t & 127;
    float s = 0.f;
    #pragma unroll
    for (int j = 0; j < 4; ++j) s += __expf(CLS[(nn * 128 + r) * 4 + j]);
    S2[t] = s;
    S2[256 + t] = 0.f;
    S2[512 + t] = 0.f;
    S2[768 + t] = 0.f;
    for (int i = 0; i < 16; ++i) {
      int o = t * 16 + i;                                 // [n][h][kc][vc]
      int n2 = o >> 11;
      int rem = o & 2047;
      int h = rem >> 8;
      int kc = (rem >> 4) & 15;
      int vc = rem & 15;
      float a = 0.f;
      #pragma unroll
      for (int j = 0; j < 4; ++j)
        a += __expf(CLS[(n2 * 128 + h * 16 + kc) * 4 + j]) *
             CLS[(n2 * 128 + h * 16 + vc) * 4 + j];
      Cnum2[o] = a;
      Cnum2[4096 + o] = 0.f;
      Cnum2[8192 + o] = 0.f;
      Cnum2[12288 + o] = 0.f;
    }
  }
}

// ---- reduce kernel: 1024 blocks x 2 tiles of 64 cols. ONE barrier per tile:
//      xT double-buffered (kills WAR), S computed from registers (kills the
//      only cross-wave ev read), ctx-MFMA reads only this wave's own ev rows
//      (same-wave LDS write->read needs no barrier, same guarantee as kB's qT).
__global__ __launch_bounds__(256) void kA(
    const float* __restrict__ x, const float* __restrict__ bk,
    const float* __restrict__ bv, float* __restrict__ S2,
    float* __restrict__ Cnum2, const u16* __restrict__ wkv) {
  __shared__ __align__(16) u16 xT[2][64][136];  // [buf][col][ch]
  __shared__ __align__(16) u16 ev[256][72];     // rows 0..127 = E(bf16), 128..255 = V(bf16)
  const int t = threadIdx.x;
  const int w = t >> 6, lane = t & 63;
  const int quad = lane >> 4, lm = lane & 15;
  const int n = blockIdx.x >> 9;                // 1024 blocks
  const int l0base = (blockIdx.x & 511) << 7;   // 128 cols per block
  const int slot = blockIdx.x & 3;              // 4 atomic slots
  const int sc = t >> 4;
  const int sl4 = t & 15;

  float4 pf[8];
  #pragma unroll
  for (int i = 0; i < 8; ++i) {
    int c = i * 16 + sc;
    pf[i] = *(const float4*)(x + (((size_t)(n * 128 + c)) << 16) + l0base + sl4 * 4);
  }

  // W fragments: wave w owns key row-blocks {2w,2w+1} and value row-blocks {8+2w,8+2w+1}
  bf16x8 wf[4][4];
  #pragma unroll
  for (int mt = 0; mt < 4; ++mt) {
    int rb = (mt < 2) ? (2 * w + mt) : (8 + 2 * w + (mt - 2));
    #pragma unroll
    for (int ks = 0; ks < 4; ++ks)
      wf[mt][ks] = *(const bf16x8*)(wkv + (((rb * 4 + ks) * 64 + lane) * 8));
  }
  float bias_[4][4];
  #pragma unroll
  for (int mt = 0; mt < 4; ++mt)
    #pragma unroll
    for (int j = 0; j < 4; ++j) {
      int r = w * 32 + (mt & 1) * 16 + quad * 4 + j;
      bias_[mt][j] = (mt < 2) ? bk[r] : bv[r];
    }

  floatx4 z4 = {0.f, 0.f, 0.f, 0.f};
  floatx4 cacc[2] = {z4, z4};                   // context accumulators (2 heads per wave)
  float sacc[2][4] = {{0.f, 0.f, 0.f, 0.f}, {0.f, 0.f, 0.f, 0.f}};

  for (int tile = 0; tile < 2; ++tile) {
    u16 (*xb)[136] = xT[tile];                  // 2 tiles / 2 buffers: no reuse, no WAR
    #pragma unroll
    for (int i = 0; i < 8; ++i) {
      int cc = i * 16 + sc;
      int col = sl4 * 4;
      xb[col + 0][cc] = f2b(pf[i].x);
      xb[col + 1][cc] = f2b(pf[i].y);
      xb[col + 2][cc] = f2b(pf[i].z);
      xb[col + 3][cc] = f2b(pf[i].w);
    }
    __syncthreads();                            // the only barrier per tile (RAW on xb)

    floatx4 acc[4][4];
    #pragma unroll
    for (int mt = 0; mt < 4; ++mt)
      #pragma unroll
      for (int nt = 0; nt < 4; ++nt) acc[mt][nt] = z4;

    #pragma unroll
    for (int nt = 0; nt < 4; ++nt)
      #pragma unroll
      for (int ks = 0; ks < 4; ++ks) {
        bf16x8 b = *(const bf16x8*)(&xb[nt * 16 + lm][ks * 32 + quad * 8]);
        #pragma unroll
        for (int mt = 0; mt < 4; ++mt)
          acc[mt][nt] = __builtin_amdgcn_mfma_f32_16x16x32_bf16(wf[mt][ks], b, acc[mt][nt], 0, 0, 0);
      }

    // prefetch next tile early: overlaps exp/ev-write epilogue + ctx MFMAs
    if (tile == 0) {
      #pragma unroll
      for (int i = 0; i < 8; ++i) {
        int c = i * 16 + sc;
        pf[i] = *(const float4*)(x + (((size_t)(n * 128 + c)) << 16) + l0base + 64 + sl4 * 4);
      }
    }

    // epilogue: bias, exp on key rows, write E/V bf16 to LDS; S partials from
    // the ROUNDED E values (matches previous numerics) straight into registers.
    #pragma unroll
    for (int mt = 0; mt < 4; ++mt)
      #pragma unroll
      for (int j = 0; j < 4; ++j) {
        int R = ((mt < 2) ? 0 : 128) + w * 32 + (mt & 1) * 16 + quad * 4 + j;
        #pragma unroll
        for (int nt = 0; nt < 4; ++nt) {
          float v = acc[mt][nt][j] + bias_[mt][j];
          if (mt < 2) {
            v = __expf(v);
            u16 b = f2b(v);
            ev[R][nt * 16 + lm] = b;
            sacc[mt][j] += b2f(b);
          } else {
            ev[R][nt * 16 + lm] = f2b(v);
          }
        }
      }

    // context: D[kc][vc] += sum_l E[h*16+kc,l] * V[h*16+vc,l]
    // reads ONLY rows this wave just wrote -> same-wave DS ordering, no barrier
    #pragma unroll
    for (int hh = 0; hh < 2; ++hh) {
      int h = w * 2 + hh;
      #pragma unroll
      for (int ks = 0; ks < 2; ++ks) {
        bf16x8 aE = *(const bf16x8*)(&ev[h * 16 + lm][ks * 32 + quad * 8]);
        bf16x8 bV = *(const bf16x8*)(&ev[128 + h * 16 + lm][ks * 32 + quad * 8]);
        cacc[hh] = __builtin_amdgcn_mfma_f32_16x16x32_bf16(aE, bV, cacc[hh], 0, 0, 0);
      }
    }
  }

  // one atomic set per block, 4-slot to keep per-address contention constant
  float* Cn = Cnum2 + slot * 4096;
  #pragma unroll
  for (int hh = 0; hh < 2; ++hh) {
    int h = w * 2 + hh;
    #pragma unroll
    for (int j = 0; j < 4; ++j)
      atomicAdd(&Cn[((n * 8 + h) * 16 + quad * 4 + j) * 16 + lm], cacc[hh][j]);
  }
  // S: reduce row partials over the 16 lm lanes, then one atomic per row
  #pragma unroll
  for (int mt = 0; mt < 2; ++mt)
    #pragma unroll
    for (int j = 0; j < 4; ++j) {
      float s = sacc[mt][j];
      s += __shfl_xor(s, 1);
      s += __shfl_xor(s, 2);
      s += __shfl_xor(s, 4);
      s += __shfl_xor(s, 8);
      if (lm == 0)
        atomicAdd(&S2[slot * 256 + n * 128 + w * 32 + mt * 16 + quad * 4 + j], s);
    }
}

// ---- M kernel: M[n] = Wr * ctx_n  (128x128 per batch), packed as MFMA A-frags.
//      Also emits context_last + CLS_out (moved out of kB).
__global__ __launch_bounds__(256) void kM(
    const float* __restrict__ Wr, const float* __restrict__ CLS,
    const float* __restrict__ S2, const float* __restrict__ Cnum2,
    u16* __restrict__ mfrag, float* __restrict__ out) {
  __shared__ float ctxn[4096];                  // [n][h][kc][vc]
  const int t = threadIdx.x;
  // row (n*128 + h*16 + kc) of every o = t*16+i is exactly t -> no barrier needed here
  float sinv = 1.f / (S2[t] + S2[256 + t] + S2[512 + t] + S2[768 + t]);
  #pragma unroll
  for (int i = 0; i < 16; ++i) {
    int o = t * 16 + i;
    ctxn[o] = (Cnum2[o] + Cnum2[4096 + o] + Cnum2[8192 + o] + Cnum2[12288 + o]) * sinv;
  }
  __syncthreads();

  if (blockIdx.x == 0) {
    for (int e = t; e < 512; e += 256) {        // context_last = ctx_n[:, head 7]
      int nn = e >> 8, kc = (e >> 4) & 15, vc = e & 15;
      out[OUT_CTX + e] = ctxn[((nn * 8 + 7) * 16 + kc) * 16 + vc];
    }
    if (t < 128) {                              // CLS_out (head 7, 4 CLS columns)
      int nn = t >> 6, vc = (t >> 2) & 15, j = t & 3;
      float den = 0.f, num = 0.f;
      #pragma unroll
      for (int kc = 0; kc < 16; ++kc) {
        float e_ = __expf(CLS[(nn * 128 + 112 + kc) * 4 + j]);
        den += e_;
        num += e_ * ctxn[((nn * 8 + 7) * 16 + kc) * 16 + vc];
      }
      out[OUT_CLS + t] = num / den;
    }
  }

  // M[o][h*16+k] = sum_v Wr[o][h*16+v] * ctxn[n][h][k][v], packed A-frag order
  #pragma unroll
  for (int i = 0; i < 8; ++i) {
    int e = blockIdx.x * 2048 + i * 256 + t;    // 16 blocks x 2048 = 32768
    int nn = e >> 14;
    int rem = e & 16383;
    int rb = rem >> 11;
    int ks = (rem >> 9) & 3;
    int ln = (rem >> 3) & 63;
    int j = rem & 7;
    int o = rb * 16 + (ln & 15);
    int cc = ks * 32 + (ln >> 4) * 8 + j;
    int h = cc >> 4, k = cc & 15;
    float m = 0.f;
    #pragma unroll
    for (int v = 0; v < 16; ++v)
      m += Wr[o * 128 + h * 16 + v] * ctxn[((nn * 8 + h) * 16 + k) * 16 + v];
    mfrag[e] = f2b(m);
  }
}

// ---- map kernel: out = M * softmax_q(Wq x + bq) + br. 1024 blocks x 2 tiles.
//      LDS = xT + qT only (34816 B -> 4 blocks/CU); att stage algebraically
//      folded into M, so ONE extra GEMM instead of ctx-GEMM + Wr-GEMM.
__global__ __launch_bounds__(256) void kB(
    const float* __restrict__ x, const float* __restrict__ bq,
    const float* __restrict__ br, const u16* __restrict__ wqf,
    const u16* __restrict__ mfrag, float* __restrict__ out) {
  __shared__ __align__(16) u16 xT[64][136];
  __shared__ __align__(16) u16 qT[64][136];     // softmaxed queries, [col][ch] bf16
  const int t = threadIdx.x;
  const int w = t >> 6, lane = t & 63;
  const int quad = lane >> 4, lm = lane & 15;
  const int n = blockIdx.x >> 9;
  const int l0base = (blockIdx.x & 511) << 7;
  const int sc = t >> 4;
  const int sl4 = t & 15;

  float4 pf[8];
  #pragma unroll
  for (int i = 0; i < 8; ++i) {
    int c = i * 16 + sc;
    pf[i] = *(const float4*)(x + (((size_t)(n * 128 + c)) << 16) + l0base + sl4 * 4);
  }

  bf16x8 wq[2][4], mA[2][4];
  #pragma unroll
  for (int mt = 0; mt < 2; ++mt)
    #pragma unroll
    for (int ks = 0; ks < 4; ++ks) {
      wq[mt][ks] = *(const bf16x8*)(wqf + ((((w * 2 + mt) * 4 + ks) * 64 + lane) * 8));
      mA[mt][ks] = *(const bf16x8*)(mfrag + ((((n * 8 + w * 2 + mt) * 4 + ks) * 64 + lane) * 8));
    }

  float bqv_[2][4], brv[2][4];
  #pragma unroll
  for (int mt = 0; mt < 2; ++mt)
    #pragma unroll
    for (int j = 0; j < 4; ++j) {
      bqv_[mt][j] = bq[(w * 2 + mt) * 16 + quad * 4 + j];
      brv[mt][j] = br[(w * 2 + mt) * 16 + quad * 4 + j];
    }

  floatx4 z4 = {0.f, 0.f, 0.f, 0.f};

  for (int tile = 0; tile < 2; ++tile) {
    int l0 = l0base + tile * 64;
    #pragma unroll
    for (int i = 0; i < 8; ++i) {
      int cc = i * 16 + sc;
      int col = sl4 * 4;
      xT[col + 0][cc] = f2b(pf[i].x);
      xT[col + 1][cc] = f2b(pf[i].y);
      xT[col + 2][cc] = f2b(pf[i].z);
      xT[col + 3][cc] = f2b(pf[i].w);
    }
    __syncthreads();                            // barrier A (xT RAW + qT WAR)

    floatx4 acc[2][4];
    #pragma unroll
    for (int mt = 0; mt < 2; ++mt)
      #pragma unroll
      for (int nt = 0; nt < 4; ++nt) acc[mt][nt] = z4;

    #pragma unroll
    for (int nt = 0; nt < 4; ++nt)
      #pragma unroll
      for (int ks = 0; ks < 4; ++ks) {
        bf16x8 b = *(const bf16x8*)(&xT[nt * 16 + lm][ks * 32 + quad * 8]);
        #pragma unroll
        for (int mt = 0; mt < 2; ++mt)
          acc[mt][nt] = __builtin_amdgcn_mfma_f32_16x16x32_bf16(wq[mt][ks], b, acc[mt][nt], 0, 0, 0);
      }

    // per-column softmax over the 16 channels of each head (wave-local)
    #pragma unroll
    for (int mt = 0; mt < 2; ++mt) {
      int h = w * 2 + mt;
      #pragma unroll
      for (int nt = 0; nt < 4; ++nt) {
        float e[4];
        float ssum = 0.f;
        #pragma unroll
        for (int j = 0; j < 4; ++j) {
          e[j] = __expf(acc[mt][nt][j] + bqv_[mt][j]);
          ssum += e[j];
        }
        ssum += __shfl_xor(ssum, 16);
        ssum += __shfl_xor(ssum, 32);
        float inv = 1.f / ssum;
        #pragma unroll
        for (int j = 0; j < 4; ++j)
          qT[nt * 16 + lm][h * 16 + quad * 4 + j] = f2b(e[j] * inv);
      }
    }

    // prefetch next tile (overlaps barrier + final GEMM)
    if (tile == 0) {
      #pragma unroll
      for (int i = 0; i < 8; ++i) {
        int c = i * 16 + sc;
        pf[i] = *(const float4*)(x + (((size_t)(n * 128 + c)) << 16) + l0base + 64 + sl4 * 4);
      }
    }
    __syncthreads();                            // barrier B (all heads' q channels ready)

    floatx4 acc2[2][4];
    #pragma unroll
    for (int mt = 0; mt < 2; ++mt)
      #pragma unroll
      for (int nt = 0; nt < 4; ++nt) acc2[mt][nt] = z4;

    #pragma unroll
    for (int nt = 0; nt < 4; ++nt)
      #pragma unroll
      for (int ks = 0; ks < 4; ++ks) {
        bf16x8 b = *(const bf16x8*)(&qT[nt * 16 + lm][ks * 32 + quad * 8]);
        #pragma unroll
        for (int mt = 0; mt < 2; ++mt)
          acc2[mt][nt] = __builtin_amdgcn_mfma_f32_16x16x32_bf16(mA[mt][ks], b, acc2[mt][nt], 0, 0, 0);
      }

    #pragma unroll
    for (int mt = 0; mt < 2; ++mt)
      #pragma unroll
      for (int j = 0; j < 4; ++j) {
        int R = (w * 2 + mt) * 16 + quad * 4 + j;
        #pragma unroll
        for (int nt = 0; nt < 4; ++nt)
          out[(((size_t)(n * 128 + R)) << 16) + l0 + nt * 16 + lm] = acc2[mt][nt][j] + brv[mt][j];
      }
  }
}

extern "C" void kernel_launch(void* const* d_in, const int* in_sizes, int n_in,
                              void* d_out, int out_size, void* d_ws, size_t ws_size,
                              hipStream_t stream) {
  const float* x   = (const float*)d_in[0];
  const float* CLS = (const float*)d_in[1];
  const float* Wk  = (const float*)d_in[2];
  const float* bk  = (const float*)d_in[3];
  const float* Wq  = (const float*)d_in[4];
  const float* bq  = (const float*)d_in[5];
  const float* Wv  = (const float*)d_in[6];
  const float* bv  = (const float*)d_in[7];
  const float* Wr  = (const float*)d_in[8];
  const float* br  = (const float*)d_in[9];
  float* out = (float*)d_out;
  char* ws = (char*)d_ws;
  float* S2    = (float*)(ws + 0);        // 4 slots x 256 f32   = 4096 B
  float* Cnum2 = (float*)(ws + 4096);     // 4 slots x 4096 f32  = 65536 B
  u16* wkv     = (u16*)(ws + 69632);      // 16*4*64*8 bf16      = 65536 B
  u16* wqf     = (u16*)(ws + 135168);     // 8*4*64*8 bf16       = 32768 B
  u16* mfrag   = (u16*)(ws + 167936);     // 2*8*4*64*8 bf16     = 65536 B

  kP<<<25, 256, 0, stream>>>(Wk, Wq, Wv, CLS, S2, Cnum2, wkv, wqf);
  kA<<<1024, 256, 0, stream>>>(x, bk, bv, S2, Cnum2, wkv);
  kM<<<16, 256, 0, stream>>>(Wr, CLS, S2, Cnum2, mfrag, out);
  kB<<<1024, 256, 0, stream>>>(x, bq, br, wqf, mfrag, out);
}